// Round 8
// baseline (206.131 us; speedup 1.0000x reference)
//
#include <hip/hip_runtime.h>
#include <hip/hip_bf16.h>
#include <math.h>

#define BATCH      2048
#define IN_DIM     784
#define HIDDEN     512
#define STYLE      128
#define NUM_LABELS 10
#define FC1_STRIDE ((IN_DIM + 1) * HIDDEN)   // 785*512
#define FC2_STRIDE ((HIDDEN + 1) * STYLE)    // 513*128
#define KP1        832                        // IN_DIM padded to mult of 64
#define TB2        32                         // rows per fused tile
#define MAXT2      80                         // >= max sum(ceil(c_L/32)) = 73

// ---- meta (int) layout at d_ws byte 0 ----
#define META_NTILES 31
#define META_TILES  32      // 3 ints per tile (L,pstart,nrows), 80 tiles -> ends 272
#define META_PERM   288

// ---- bf16 workspace layout (byte offsets) ----
#define W1B_OFF  16384ULL                               // [10][512][832] bf16 ([L][n][k])
#define W2B_OFF  (W1B_OFF + 10ULL*HIDDEN*KP1*2)         // [10][128][512] bf16 ([L][n][k])
#define WS_NEED  (W2B_OFF + 10ULL*STYLE*HIDDEN*2)       // ~9.8 MB

#define W1_KB 26                                        // 832/32
#define W1_NB 16                                        // 512/32
#define W2_KB 16                                        // 512/32
#define W2_NB 4                                         // 128/32
#define W1_BLOCKS (W1_KB*W1_NB*NUM_LABELS)              // 4160
#define W2_BLOCKS (W2_KB*W2_NB*NUM_LABELS)              // 640

// dynamic LDS for k_mlp: rows(128) + As 32x72(4608) + Bs 512x72(73728) + h1 32x520(33280)
#define SM_AS_OFF   128
#define SM_BS_OFF   (SM_AS_OFF + 32*72*2)
#define SM_H1_OFF   (SM_BS_OFF + 512*72*2)
#define SM_BYTES    (SM_H1_OFF + 32*520*2)              // 111744 B < 160 KiB

typedef short short8  __attribute__((ext_vector_type(8)));
typedef float float4e __attribute__((ext_vector_type(4)));

__device__ __forceinline__ ushort f2b(float v) {
    __hip_bfloat16 h = __float2bfloat16(v);
    return *reinterpret_cast<ushort*>(&h);
}

// ---------- prep: block 0 = meta (32-row tiles); rest = weight transpose+convert ----------
__global__ void k_prep(const int* __restrict__ m, const float* __restrict__ fc1t,
                       const float* __restrict__ fc2t, int* __restrict__ meta,
                       ushort* __restrict__ w1b, ushort* __restrict__ w2b) {
    const int tid = threadIdx.x;
    int bid = blockIdx.x;

    __shared__ int cnt[NUM_LABELS], curs[NUM_LABELS], offs[NUM_LABELS + 1];
    __shared__ int permS[BATCH];
    __shared__ float tile[32][33];

    if (bid == 0) {
        if (tid < NUM_LABELS) { cnt[tid] = 0; curs[tid] = 0; }
        __syncthreads();
        for (int b = tid; b < BATCH; b += 256) atomicAdd(&cnt[m[b]], 1);
        __syncthreads();
        if (tid == 0) {
            int off = 0;
            for (int L = 0; L < NUM_LABELS; ++L) { offs[L] = off; off += cnt[L]; }
            offs[NUM_LABELS] = off;
        }
        __syncthreads();
        for (int b = tid; b < BATCH; b += 256) {
            int L = m[b];
            int r = atomicAdd(&curs[L], 1);
            permS[offs[L] + r] = b;
        }
        __syncthreads();
        for (int i = tid; i < BATCH; i += 256) meta[META_PERM + i] = permS[i];
        if (tid == 0) {
            int idx = 0;
            for (int L = 0; L < NUM_LABELS; ++L) {
                int c = cnt[L], off = offs[L];
                for (int t = 0; t < c; t += TB2) {
                    meta[META_TILES + idx * 3 + 0] = L;
                    meta[META_TILES + idx * 3 + 1] = off + t;
                    meta[META_TILES + idx * 3 + 2] = min(TB2, c - t);
                    ++idx;
                }
            }
            meta[META_NTILES] = idx;
        }
        return;
    }

    bid -= 1;
    const float* src; ushort* dst; int Kvalid, Kpad, N, kb, nb, L; size_t srcL, dstL;
    if (bid < W1_BLOCKS) {
        kb = bid % W1_KB; nb = (bid / W1_KB) % W1_NB; L = bid / (W1_KB * W1_NB);
        src = fc1t; dst = w1b; Kvalid = IN_DIM; Kpad = KP1; N = HIDDEN;
        srcL = FC1_STRIDE; dstL = (size_t)HIDDEN * KP1;
    } else {
        bid -= W1_BLOCKS;
        kb = bid % W2_KB; nb = (bid / W2_KB) % W2_NB; L = bid / (W2_KB * W2_NB);
        src = fc2t; dst = w2b; Kvalid = HIDDEN; Kpad = HIDDEN; N = STYLE;
        srcL = FC2_STRIDE; dstL = (size_t)STYLE * HIDDEN;
    }
    const int tx = tid & 31, ty = tid >> 5;
    const int k0 = kb * 32, n0 = nb * 32;
    for (int r = ty; r < 32; r += 8) {
        int k = k0 + r;
        tile[r][tx] = (k < Kvalid) ? src[(size_t)L * srcL + (size_t)k * N + n0 + tx] : 0.f;
    }
    __syncthreads();
    for (int r = ty; r < 32; r += 8) {
        int n = n0 + r;
        dst[(size_t)L * dstL + (size_t)n * Kpad + k0 + tx] = f2b(tile[tx][r]);
    }
}

// ---------- fused MLP: one block = 32 batch rows, h1 lives in LDS ----------
__global__ __launch_bounds__(256, 1)
void k_mlp(const float* __restrict__ x, const float* __restrict__ fc1t,
           const float* __restrict__ fc2t, const ushort* __restrict__ w1b,
           const ushort* __restrict__ w2b, const int* __restrict__ meta,
           float* __restrict__ out) {
    const int t = blockIdx.x;
    if (t >= meta[META_NTILES]) return;
    const int L      = meta[META_TILES + 3*t + 0];
    const int pstart = meta[META_TILES + 3*t + 1];
    const int nrows  = meta[META_TILES + 3*t + 2];

    extern __shared__ __align__(16) char smem[];
    int*    rowsS       = (int*)smem;
    ushort (*As)[72]    = (ushort(*)[72])(smem + SM_AS_OFF);
    ushort (*Bs)[72]    = (ushort(*)[72])(smem + SM_BS_OFF);   // 512 x 72
    ushort (*h1S)[520]  = (ushort(*)[520])(smem + SM_H1_OFF);  // 32 x 520

    const int tid = threadIdx.x;
    if (tid < TB2) rowsS[tid] = (tid < nrows) ? meta[META_PERM + pstart + tid] : -1;
    __syncthreads();

    const int lane = tid & 63, wv = tid >> 6, qd = lane >> 4, ln16 = lane & 15;

    // ---------------- phase 1: h1[32][512] = relu(x . W1 + b1) ----------------
    const int ar = tid >> 3, akc = tid & 7;          // A staging: row 0..31, 8-elem chunk
    const int arow = rowsS[ar];
    const float* __restrict__ xr = x + (size_t)(arow < 0 ? 0 : arow) * IN_DIM;
    const ushort* __restrict__ wbase = w1b + (size_t)L * HIDDEN * KP1;

    float4e acc[2][8] = {};
    float4 a0 = make_float4(0.f,0.f,0.f,0.f), a1 = a0;
    uint4 bpf[16];
    {
        const int ka = akc * 8;
        if (arow >= 0 && ka < IN_DIM) {              // 784 % 8 == 0: all-valid or all-pad
            a0 = *(const float4*)(xr + ka);
            a1 = *(const float4*)(xr + ka + 4);
        }
#pragma unroll
        for (int r = 0; r < 16; ++r) {
            const int idx = r*256 + tid, n = idx >> 3, c = idx & 7;
            bpf[r] = *(const uint4*)(wbase + (size_t)n * KP1 + c*8);
        }
    }

    for (int it = 0; it < KP1/64; ++it) {
        {
            ushort av[8] = {f2b(a0.x), f2b(a0.y), f2b(a0.z), f2b(a0.w),
                            f2b(a1.x), f2b(a1.y), f2b(a1.z), f2b(a1.w)};
            *(uint4*)&As[ar][akc*8] = *(const uint4*)av;
        }
#pragma unroll
        for (int r = 0; r < 16; ++r) {
            const int idx = r*256 + tid, n = idx >> 3, c = idx & 7;
            *(uint4*)&Bs[n][c*8] = bpf[r];
        }
        __syncthreads();

        if (it + 1 < KP1/64) {                       // prefetch under the MFMAs
            const int k0 = (it+1)*64, ka = k0 + akc*8;
            a0 = make_float4(0.f,0.f,0.f,0.f); a1 = a0;
            if (arow >= 0 && ka < IN_DIM) {
                a0 = *(const float4*)(xr + ka);
                a1 = *(const float4*)(xr + ka + 4);
            }
#pragma unroll
            for (int r = 0; r < 16; ++r) {
                const int idx = r*256 + tid, n = idx >> 3, c = idx & 7;
                bpf[r] = *(const uint4*)(wbase + (size_t)n * KP1 + k0 + c*8);
            }
        }

#pragma unroll
        for (int s = 0; s < 2; ++s) {
            short8 af0 = *(const short8*)&As[ln16][s*32 + qd*8];
            short8 af1 = *(const short8*)&As[16 + ln16][s*32 + qd*8];
#pragma unroll
            for (int cf = 0; cf < 8; ++cf) {
                short8 bf = *(const short8*)&Bs[wv*128 + cf*16 + ln16][s*32 + qd*8];
                acc[0][cf] = __builtin_amdgcn_mfma_f32_16x16x32_bf16(af0, bf, acc[0][cf], 0,0,0);
                acc[1][cf] = __builtin_amdgcn_mfma_f32_16x16x32_bf16(af1, bf, acc[1][cf], 0,0,0);
            }
        }
        __syncthreads();
    }

    // h1 -> LDS (bias + relu)
    {
        const float* __restrict__ b1p = fc1t + (size_t)L*FC1_STRIDE + (size_t)IN_DIM*HIDDEN;
#pragma unroll
        for (int cf = 0; cf < 8; ++cf) {
            const int col = wv*128 + cf*16 + ln16;
            const float bs = b1p[col];
#pragma unroll
            for (int rf = 0; rf < 2; ++rf)
#pragma unroll
                for (int i = 0; i < 4; ++i) {
                    const int row = rf*16 + qd*4 + i;
                    h1S[row][col] = f2b(fmaxf(acc[rf][cf][i] + bs, 0.f));
                }
        }
    }
    __syncthreads();

    // ---------------- phase 2: out[32][128] = sigmoid(h1 . W2 + b2) ----------------
    const ushort* __restrict__ w2base = w2b + (size_t)L * STYLE * HIDDEN;
    ushort (*Bs2)[136] = (ushort(*)[136])&Bs[0][0];   // 128 x 136, reuses Bs storage

    float4e acc2[2][2] = {};
    uint4 b2pf[8];
#pragma unroll
    for (int r = 0; r < 8; ++r) {
        const int idx = r*256 + tid, n = idx >> 4, c = idx & 15;
        b2pf[r] = *(const uint4*)(w2base + (size_t)n * HIDDEN + c*8);
    }
    for (int it = 0; it < 4; ++it) {
#pragma unroll
        for (int r = 0; r < 8; ++r) {
            const int idx = r*256 + tid, n = idx >> 4, c = idx & 15;
            *(uint4*)&Bs2[n][c*8] = b2pf[r];
        }
        __syncthreads();
        if (it + 1 < 4) {
            const int k0 = (it+1)*128;
#pragma unroll
            for (int r = 0; r < 8; ++r) {
                const int idx = r*256 + tid, n = idx >> 4, c = idx & 15;
                b2pf[r] = *(const uint4*)(w2base + (size_t)n * HIDDEN + k0 + c*8);
            }
        }
#pragma unroll
        for (int s = 0; s < 4; ++s) {
            short8 af0 = *(const short8*)&h1S[ln16][it*128 + s*32 + qd*8];
            short8 af1 = *(const short8*)&h1S[16 + ln16][it*128 + s*32 + qd*8];
#pragma unroll
            for (int cf = 0; cf < 2; ++cf) {
                short8 bf = *(const short8*)&Bs2[wv*32 + cf*16 + ln16][s*32 + qd*8];
                acc2[0][cf] = __builtin_amdgcn_mfma_f32_16x16x32_bf16(af0, bf, acc2[0][cf], 0,0,0);
                acc2[1][cf] = __builtin_amdgcn_mfma_f32_16x16x32_bf16(af1, bf, acc2[1][cf], 0,0,0);
            }
        }
        __syncthreads();
    }

    {
        const float* __restrict__ b2p = fc2t + (size_t)L*FC2_STRIDE + (size_t)HIDDEN*STYLE;
#pragma unroll
        for (int cf = 0; cf < 2; ++cf) {
            const int col = wv*32 + cf*16 + ln16;
            const float bs = b2p[col];
#pragma unroll
            for (int rf = 0; rf < 2; ++rf)
#pragma unroll
                for (int i = 0; i < 4; ++i) {
                    const int row = rf*16 + qd*4 + i;
                    if (row < nrows) {
                        const int orow = rowsS[row];
                        out[(size_t)orow*STYLE + col] = 1.f / (1.f + __expf(-(acc2[rf][cf][i] + bs)));
                    }
                }
        }
    }
}

// ---------- fallback (ws too small): fused per-row, slow but correct ----------
__launch_bounds__(256)
__global__ void k_naive(const float* __restrict__ x, const int* __restrict__ m,
                        const float* __restrict__ fc1t, const float* __restrict__ fc2t,
                        float* __restrict__ out) {
    __shared__ float xs[IN_DIM];
    __shared__ float h1[HIDDEN];
    const int b = blockIdx.x, tid = threadIdx.x, L = m[b];
    for (int k = tid; k < IN_DIM; k += 256) xs[k] = x[(size_t)b * IN_DIM + k];
    __syncthreads();
    const float* __restrict__ W1 = fc1t + (size_t)L * FC1_STRIDE;
    for (int j = tid; j < HIDDEN; j += 256) {
        float acc = W1[(size_t)IN_DIM * HIDDEN + j];
        for (int k = 0; k < IN_DIM; ++k) acc = fmaf(xs[k], W1[(size_t)k * HIDDEN + j], acc);
        h1[j] = fmaxf(acc, 0.f);
    }
    __syncthreads();
    const float* __restrict__ W2 = fc2t + (size_t)L * FC2_STRIDE;
    for (int j = tid; j < STYLE; j += 256) {
        float acc = W2[(size_t)HIDDEN * STYLE + j];
        for (int k = 0; k < HIDDEN; ++k) acc = fmaf(h1[k], W2[(size_t)k * STYLE + j], acc);
        out[(size_t)b * STYLE + j] = 1.f / (1.f + __expf(-acc));
    }
}

extern "C" void kernel_launch(void* const* d_in, const int* in_sizes, int n_in,
                              void* d_out, int out_size, void* d_ws, size_t ws_size,
                              hipStream_t stream) {
    const float* x    = (const float*)d_in[0];
    const int*   m    = (const int*)d_in[1];
    const float* fc1t = (const float*)d_in[2];
    const float* fc2t = (const float*)d_in[3];
    float* out = (float*)d_out;

    if (ws_size >= WS_NEED) {
        int*    meta = (int*)d_ws;
        ushort* w1b  = (ushort*)((char*)d_ws + W1B_OFF);
        ushort* w2b  = (ushort*)((char*)d_ws + W2B_OFF);

        k_prep<<<1 + W1_BLOCKS + W2_BLOCKS, 256, 0, stream>>>(m, fc1t, fc2t, meta, w1b, w2b);
        k_mlp<<<MAXT2, 256, SM_BYTES, stream>>>(x, fc1t, fc2t, w1b, w2b, meta, out);
    } else {
        k_naive<<<BATCH, 256, 0, stream>>>(x, m, fc1t, fc2t, out);
    }
}

// Round 9
// 101.320 us; speedup vs baseline: 2.0345x; 2.0345x over previous
//
#include <hip/hip_runtime.h>
#include <hip/hip_bf16.h>
#include <math.h>

#define BATCH      2048
#define IN_DIM     784
#define HIDDEN     512
#define STYLE      128
#define NUM_LABELS 10
#define FC1_STRIDE ((IN_DIM + 1) * HIDDEN)   // 785*512
#define FC2_STRIDE ((HIDDEN + 1) * STYLE)    // 513*128
#define KP1        832                        // IN_DIM padded to mult of 64
#define TB         64
#define BK         64
#define MAX_TILES  48    // >= max possible sum(ceil(c_L/64)) = 41

// ---- meta (int) layout at d_ws byte 0 ----
#define META_NTILES 31
#define META_TILES  32     // 3 ints per tile: label,pstart,nrows
#define META_PERM   176

// ---- bf16 workspace layout (byte offsets) ----
#define W1B_OFF  16384ULL                               // [10][512][832] bf16 ([L][n][k])
#define W2B_OFF  (W1B_OFF + 10ULL*HIDDEN*KP1*2)         // [10][128][512] bf16 ([L][n][k])
#define H1B_OFF  (W2B_OFF + 10ULL*STYLE*HIDDEN*2)       // [2048][512] bf16 (permuted rows)
#define BF16_NEED (H1B_OFF + (size_t)BATCH*HIDDEN*2)    // ~11.9 MB

#define W1_KB 26                                        // 832/32
#define W1_NB 16                                        // 512/32
#define W2_KB 16                                        // 512/32
#define W2_NB 4                                         // 128/32
#define W1_BLOCKS (W1_KB*W1_NB*NUM_LABELS)              // 4160
#define W2_BLOCKS (W2_KB*W2_NB*NUM_LABELS)              // 640

typedef short short8  __attribute__((ext_vector_type(8)));
typedef float float4e __attribute__((ext_vector_type(4)));

__device__ __forceinline__ ushort f2b(float v) {
    __hip_bfloat16 h = __float2bfloat16(v);
    return *reinterpret_cast<ushort*>(&h);
}

// ---------- prep: block 0 = meta; rest = weight transpose+convert (round-3 exact) ----------
__global__ void k_prep(const int* __restrict__ m, const float* __restrict__ fc1t,
                       const float* __restrict__ fc2t, int* __restrict__ meta,
                       ushort* __restrict__ w1b, ushort* __restrict__ w2b) {
    const int tid = threadIdx.x;
    int bid = blockIdx.x;

    __shared__ int cnt[NUM_LABELS], curs[NUM_LABELS], offs[NUM_LABELS + 1];
    __shared__ int permS[BATCH];
    __shared__ float tile[32][33];

    if (bid == 0) {
        if (tid < NUM_LABELS) { cnt[tid] = 0; curs[tid] = 0; }
        __syncthreads();
        for (int b = tid; b < BATCH; b += 256) atomicAdd(&cnt[m[b]], 1);
        __syncthreads();
        if (tid == 0) {
            int off = 0;
            for (int L = 0; L < NUM_LABELS; ++L) { offs[L] = off; off += cnt[L]; }
            offs[NUM_LABELS] = off;
        }
        __syncthreads();
        for (int b = tid; b < BATCH; b += 256) {
            int L = m[b];
            int r = atomicAdd(&curs[L], 1);
            permS[offs[L] + r] = b;
        }
        __syncthreads();
        for (int i = tid; i < BATCH; i += 256) meta[META_PERM + i] = permS[i];
        if (tid == 0) {
            int idx = 0;
            for (int L = 0; L < NUM_LABELS; ++L) {
                int c = cnt[L], off = offs[L];
                for (int t = 0; t < c; t += TB) {
                    meta[META_TILES + idx * 3 + 0] = L;
                    meta[META_TILES + idx * 3 + 1] = off + t;
                    meta[META_TILES + idx * 3 + 2] = min(TB, c - t);
                    ++idx;
                }
            }
            meta[META_NTILES] = idx;
        }
        return;
    }

    bid -= 1;
    const float* src; ushort* dst; int Kvalid, Kpad, N, kb, nb, L; size_t srcL, dstL;
    if (bid < W1_BLOCKS) {
        kb = bid % W1_KB; nb = (bid / W1_KB) % W1_NB; L = bid / (W1_KB * W1_NB);
        src = fc1t; dst = w1b; Kvalid = IN_DIM; Kpad = KP1; N = HIDDEN;
        srcL = FC1_STRIDE; dstL = (size_t)HIDDEN * KP1;
    } else {
        bid -= W1_BLOCKS;
        kb = bid % W2_KB; nb = (bid / W2_KB) % W2_NB; L = bid / (W2_KB * W2_NB);
        src = fc2t; dst = w2b; Kvalid = HIDDEN; Kpad = HIDDEN; N = STYLE;
        srcL = FC2_STRIDE; dstL = (size_t)STYLE * HIDDEN;
    }
    const int tx = tid & 31, ty = tid >> 5;
    const int k0 = kb * 32, n0 = nb * 32;
    for (int r = ty; r < 32; r += 8) {
        int k = k0 + r;
        tile[r][tx] = (k < Kvalid) ? src[(size_t)L * srcL + (size_t)k * N + n0 + tx] : 0.f;
    }
    __syncthreads();
    for (int r = ty; r < 32; r += 8) {
        int n = n0 + r;
        dst[(size_t)L * dstL + (size_t)n * Kpad + k0 + tx] = f2b(tile[tx][r]);
    }
}

// ---------- fc1: bf16 MFMA, BK=64, LDS DOUBLE-BUFFER (the one change vs round 7) ----------
__launch_bounds__(256)
__global__ void k_fc1m(const float* __restrict__ x, const ushort* __restrict__ w1b,
                       const float* __restrict__ fc1t, const int* __restrict__ meta,
                       ushort* __restrict__ h1b) {
    const int t = blockIdx.x;
    if (t >= meta[META_NTILES]) return;
    const int L      = meta[META_TILES + 3 * t + 0];
    const int pstart = meta[META_TILES + 3 * t + 1];
    const int nrows  = meta[META_TILES + 3 * t + 2];
    const int col0   = blockIdx.y * 64;
    const ushort* __restrict__ W = w1b + (size_t)L * HIDDEN * KP1 + (size_t)col0 * KP1;

    __shared__ int rows[TB];
    __shared__ __align__(16) ushort As[2][64][72];
    __shared__ __align__(16) ushort Bs[2][64][72];

    const int tid = threadIdx.x;
    if (tid < TB) rows[tid] = (tid < nrows) ? meta[META_PERM + pstart + tid] : -1;
    __syncthreads();

    const int sr = tid >> 2, sc = tid & 3;
    const int lane = tid & 63, wv = tid >> 6;
    const int qd = lane >> 4, ln16 = lane & 15;

    const int arow = rows[sr];
    const float* __restrict__ xr = x + (size_t)(arow < 0 ? 0 : arow) * IN_DIM;
    const uint4* __restrict__ bgp = (const uint4*)(W + (size_t)sr * KP1);

    float4e acc[4] = {};
    float4 a0, a1, a2, a3;
    uint4 b0, b1;

    // ---- load chunk 0, write to buf 0 ----
    {
        const int ka = sc * 16;
        a0 = make_float4(0.f,0.f,0.f,0.f); a1 = a0; a2 = a0; a3 = a0;
        if (arow >= 0) {
            if (ka      < IN_DIM) a0 = *(const float4*)(xr + ka);
            if (ka + 4  < IN_DIM) a1 = *(const float4*)(xr + ka + 4);
            if (ka + 8  < IN_DIM) a2 = *(const float4*)(xr + ka + 8);
            if (ka + 12 < IN_DIM) a3 = *(const float4*)(xr + ka + 12);
        }
        b0 = bgp[sc * 2 + 0];
        b1 = bgp[sc * 2 + 1];
        ushort av[16];
        av[0]=f2b(a0.x); av[1]=f2b(a0.y); av[2]=f2b(a0.z); av[3]=f2b(a0.w);
        av[4]=f2b(a1.x); av[5]=f2b(a1.y); av[6]=f2b(a1.z); av[7]=f2b(a1.w);
        av[8]=f2b(a2.x); av[9]=f2b(a2.y); av[10]=f2b(a2.z); av[11]=f2b(a2.w);
        av[12]=f2b(a3.x); av[13]=f2b(a3.y); av[14]=f2b(a3.z); av[15]=f2b(a3.w);
        *(uint4*)&As[0][sr][sc * 16 + 0] = *(const uint4*)&av[0];
        *(uint4*)&As[0][sr][sc * 16 + 8] = *(const uint4*)&av[8];
        *(uint4*)&Bs[0][sr][sc * 16 + 0] = b0;
        *(uint4*)&Bs[0][sr][sc * 16 + 8] = b1;
    }
    // ---- load chunk 1 into regs ----
    {
        const int ka = BK + sc * 16;
        a0 = make_float4(0.f,0.f,0.f,0.f); a1 = a0; a2 = a0; a3 = a0;
        if (arow >= 0) {
            if (ka      < IN_DIM) a0 = *(const float4*)(xr + ka);
            if (ka + 4  < IN_DIM) a1 = *(const float4*)(xr + ka + 4);
            if (ka + 8  < IN_DIM) a2 = *(const float4*)(xr + ka + 8);
            if (ka + 12 < IN_DIM) a3 = *(const float4*)(xr + ka + 12);
        }
        b0 = bgp[(BK >> 3) + sc * 2 + 0];
        b1 = bgp[(BK >> 3) + sc * 2 + 1];
    }

    int p = 0;
    for (int k0 = 0; k0 < KP1; k0 += BK) {
        __syncthreads();   // buf p writes (prev iter) visible; prev reads of buf 1-p done
        if (k0 + BK < KP1) {
            // write chunk k0+BK (in regs) to buf 1-p; overlaps MFMA on buf p below
            ushort av[16];
            av[0]=f2b(a0.x); av[1]=f2b(a0.y); av[2]=f2b(a0.z); av[3]=f2b(a0.w);
            av[4]=f2b(a1.x); av[5]=f2b(a1.y); av[6]=f2b(a1.z); av[7]=f2b(a1.w);
            av[8]=f2b(a2.x); av[9]=f2b(a2.y); av[10]=f2b(a2.z); av[11]=f2b(a2.w);
            av[12]=f2b(a3.x); av[13]=f2b(a3.y); av[14]=f2b(a3.z); av[15]=f2b(a3.w);
            *(uint4*)&As[1-p][sr][sc * 16 + 0] = *(const uint4*)&av[0];
            *(uint4*)&As[1-p][sr][sc * 16 + 8] = *(const uint4*)&av[8];
            *(uint4*)&Bs[1-p][sr][sc * 16 + 0] = b0;
            *(uint4*)&Bs[1-p][sr][sc * 16 + 8] = b1;
        }
        if (k0 + 2*BK < KP1) {
            // issue loads for chunk k0+2BK; a full iteration + barrier of latency cover
            const int ka = k0 + 2*BK + sc * 16;
            a0 = make_float4(0.f,0.f,0.f,0.f); a1 = a0; a2 = a0; a3 = a0;
            if (arow >= 0) {
                if (ka      < IN_DIM) a0 = *(const float4*)(xr + ka);
                if (ka + 4  < IN_DIM) a1 = *(const float4*)(xr + ka + 4);
                if (ka + 8  < IN_DIM) a2 = *(const float4*)(xr + ka + 8);
                if (ka + 12 < IN_DIM) a3 = *(const float4*)(xr + ka + 12);
            }
            b0 = bgp[((k0 + 2*BK) >> 3) + sc * 2 + 0];
            b1 = bgp[((k0 + 2*BK) >> 3) + sc * 2 + 1];
        }
#pragma unroll
        for (int s = 0; s < 2; ++s) {
            short8 af = *(const short8*)&As[p][wv * 16 + ln16][s * 32 + qd * 8];
#pragma unroll
            for (int nt = 0; nt < 4; ++nt) {
                short8 bf = *(const short8*)&Bs[p][nt * 16 + ln16][s * 32 + qd * 8];
                acc[nt] = __builtin_amdgcn_mfma_f32_16x16x32_bf16(af, bf, acc[nt], 0, 0, 0);
            }
        }
        p ^= 1;
    }

    const float* __restrict__ bias = fc1t + (size_t)L * FC1_STRIDE + (size_t)IN_DIM * HIDDEN + col0;
#pragma unroll
    for (int nt = 0; nt < 4; ++nt) {
        const int c = nt * 16 + ln16;
        const float bs = bias[c];
#pragma unroll
        for (int i = 0; i < 4; ++i) {
            const int r = wv * 16 + qd * 4 + i;
            if (r < nrows)
                h1b[(size_t)(pstart + r) * HIDDEN + col0 + c] = f2b(fmaxf(acc[nt][i] + bs, 0.f));
        }
    }
}

// ---------- fc2: bf16 MFMA, BK=64, LDS DOUBLE-BUFFER ----------
__launch_bounds__(256)
__global__ void k_fc2m(const ushort* __restrict__ h1b, const ushort* __restrict__ w2b,
                       const float* __restrict__ fc2t, const int* __restrict__ meta,
                       float* __restrict__ out) {
    const int t = blockIdx.x;
    if (t >= meta[META_NTILES]) return;
    const int L      = meta[META_TILES + 3 * t + 0];
    const int pstart = meta[META_TILES + 3 * t + 1];
    const int nrows  = meta[META_TILES + 3 * t + 2];
    const int col0   = blockIdx.y * 64;
    const ushort* __restrict__ W = w2b + (size_t)L * STYLE * HIDDEN + (size_t)col0 * HIDDEN;

    __shared__ int rows[TB];
    __shared__ __align__(16) ushort As[2][64][72];
    __shared__ __align__(16) ushort Bs[2][64][72];

    const int tid = threadIdx.x;
    if (tid < TB) rows[tid] = (tid < nrows) ? meta[META_PERM + pstart + tid] : -1;
    __syncthreads();

    const int sr = tid >> 2, sc = tid & 3;
    const int lane = tid & 63, wv = tid >> 6;
    const int qd = lane >> 4, ln16 = lane & 15;

    const bool aval = (sr < nrows);
    const uint4* __restrict__ agp = (const uint4*)(h1b + (size_t)(pstart + (aval ? sr : 0)) * HIDDEN);
    const uint4* __restrict__ bgp = (const uint4*)(W + (size_t)sr * HIDDEN);

    float4e acc[4] = {};
    uint4 a0, a1, b0, b1;

    // chunk 0 -> buf 0
    a0 = make_uint4(0u,0u,0u,0u); a1 = a0;
    if (aval) { a0 = agp[sc * 2 + 0]; a1 = agp[sc * 2 + 1]; }
    b0 = bgp[sc * 2 + 0];
    b1 = bgp[sc * 2 + 1];
    *(uint4*)&As[0][sr][sc * 16 + 0] = a0;
    *(uint4*)&As[0][sr][sc * 16 + 8] = a1;
    *(uint4*)&Bs[0][sr][sc * 16 + 0] = b0;
    *(uint4*)&Bs[0][sr][sc * 16 + 8] = b1;
    // chunk 1 -> regs
    {
        const int base = (BK >> 3) + sc * 2;
        a0 = make_uint4(0u,0u,0u,0u); a1 = a0;
        if (aval) { a0 = agp[base]; a1 = agp[base + 1]; }
        b0 = bgp[base];
        b1 = bgp[base + 1];
    }

    int p = 0;
    for (int k0 = 0; k0 < HIDDEN; k0 += BK) {
        __syncthreads();
        if (k0 + BK < HIDDEN) {
            *(uint4*)&As[1-p][sr][sc * 16 + 0] = a0;
            *(uint4*)&As[1-p][sr][sc * 16 + 8] = a1;
            *(uint4*)&Bs[1-p][sr][sc * 16 + 0] = b0;
            *(uint4*)&Bs[1-p][sr][sc * 16 + 8] = b1;
        }
        if (k0 + 2*BK < HIDDEN) {
            const int base = ((k0 + 2*BK) >> 3) + sc * 2;
            a0 = make_uint4(0u,0u,0u,0u); a1 = a0;
            if (aval) { a0 = agp[base]; a1 = agp[base + 1]; }
            b0 = bgp[base];
            b1 = bgp[base + 1];
        }
#pragma unroll
        for (int s = 0; s < 2; ++s) {
            short8 af = *(const short8*)&As[p][wv * 16 + ln16][s * 32 + qd * 8];
#pragma unroll
            for (int nt = 0; nt < 4; ++nt) {
                short8 bf = *(const short8*)&Bs[p][nt * 16 + ln16][s * 32 + qd * 8];
                acc[nt] = __builtin_amdgcn_mfma_f32_16x16x32_bf16(af, bf, acc[nt], 0, 0, 0);
            }
        }
        p ^= 1;
    }

    const float* __restrict__ bias = fc2t + (size_t)L * FC2_STRIDE + (size_t)HIDDEN * STYLE + col0;
#pragma unroll
    for (int nt = 0; nt < 4; ++nt) {
        const int c = nt * 16 + ln16;
        const float bs = bias[c];
#pragma unroll
        for (int i = 0; i < 4; ++i) {
            const int r = wv * 16 + qd * 4 + i;
            if (r < nrows) {
                const int orow = rows[r];
                out[(size_t)orow * STYLE + col0 + c] = 1.f / (1.f + __expf(-(acc[nt][i] + bs)));
            }
        }
    }
}

// ---------- fallback (ws too small): fused per-row, slow but correct ----------
__launch_bounds__(256)
__global__ void k_naive(const float* __restrict__ x, const int* __restrict__ m,
                        const float* __restrict__ fc1t, const float* __restrict__ fc2t,
                        float* __restrict__ out) {
    __shared__ float xs[IN_DIM];
    __shared__ float h1[HIDDEN];
    const int b = blockIdx.x, tid = threadIdx.x, L = m[b];
    for (int k = tid; k < IN_DIM; k += 256) xs[k] = x[(size_t)b * IN_DIM + k];
    __syncthreads();
    const float* __restrict__ W1 = fc1t + (size_t)L * FC1_STRIDE;
    for (int j = tid; j < HIDDEN; j += 256) {
        float acc = W1[(size_t)IN_DIM * HIDDEN + j];
        for (int k = 0; k < IN_DIM; ++k) acc = fmaf(xs[k], W1[(size_t)k * HIDDEN + j], acc);
        h1[j] = fmaxf(acc, 0.f);
    }
    __syncthreads();
    const float* __restrict__ W2 = fc2t + (size_t)L * FC2_STRIDE;
    for (int j = tid; j < STYLE; j += 256) {
        float acc = W2[(size_t)HIDDEN * STYLE + j];
        for (int k = 0; k < HIDDEN; ++k) acc = fmaf(h1[k], W2[(size_t)k * STYLE + j], acc);
        out[(size_t)b * STYLE + j] = 1.f / (1.f + __expf(-acc));
    }
}

extern "C" void kernel_launch(void* const* d_in, const int* in_sizes, int n_in,
                              void* d_out, int out_size, void* d_ws, size_t ws_size,
                              hipStream_t stream) {
    const float* x    = (const float*)d_in[0];
    const int*   m    = (const int*)d_in[1];
    const float* fc1t = (const float*)d_in[2];
    const float* fc2t = (const float*)d_in[3];
    float* out = (float*)d_out;

    if (ws_size >= BF16_NEED) {
        int*    meta = (int*)d_ws;
        ushort* w1b  = (ushort*)((char*)d_ws + W1B_OFF);
        ushort* w2b  = (ushort*)((char*)d_ws + W2B_OFF);
        ushort* h1b  = (ushort*)((char*)d_ws + H1B_OFF);

        k_prep<<<1 + W1_BLOCKS + W2_BLOCKS, 256, 0, stream>>>(m, fc1t, fc2t, meta, w1b, w2b);
        k_fc1m<<<dim3(MAX_TILES, HIDDEN / 64), 256, 0, stream>>>(x, w1b, fc1t, meta, h1b);
        k_fc2m<<<dim3(MAX_TILES, STYLE / 64), 256, 0, stream>>>(h1b, w2b, fc2t, meta, out);
    } else {
        k_naive<<<BATCH, 256, 0, stream>>>(x, m, fc1t, fc2t, out);
    }
}